// Round 1
// baseline (315.893 us; speedup 1.0000x reference)
//
#include <hip/hip_runtime.h>
#include <hip/hip_bf16.h>

typedef _Float16 half8 __attribute__((ext_vector_type(8)));
typedef float    f32x4 __attribute__((ext_vector_type(4)));

#define NB   8
#define NC   64
#define NH   256
#define NW   256
#define NO   64
// ws layout (bytes)
#define Y_OFF    0ull
#define Y_BYTES  (33554432ull * 2ull)          // 8*256*256*64 halves, NHWC
#define TW_OFF   (Y_OFF + Y_BYTES)
#define TW_BYTES (576ull * 64ull * 2ull)       // pre-swizzled ternary weights
#define MSW_OFF  (TW_OFF + TW_BYTES)

// ---------------------------------------------------------------------------
// Kernel 1: weight scale + ternary quantize, pre-arranged for MFMA A-fragments.
// tw2 position for W element (o,c,kh,kw):  k = (kh*3+kw)*64 + c
//   pos = ((k>>3)*64 + o)*8 + (k&7)   -> lane A-fragment = contiguous half8
// ---------------------------------------------------------------------------
__global__ __launch_bounds__(256) void wq_kernel(const float* __restrict__ W,
                                                 _Float16* __restrict__ tw2,
                                                 float* __restrict__ msw_out) {
    __shared__ float red[256];
    __shared__ float sw_sh;
    int tid = threadIdx.x;
    float s = 0.0f;
    #pragma unroll
    for (int i = 0; i < 144; ++i) s += fabsf(W[i * 256 + tid]);
    red[tid] = s;
    __syncthreads();
    for (int off = 128; off > 0; off >>= 1) {
        if (tid < off) red[tid] += red[tid + off];
        __syncthreads();
    }
    if (tid == 0) {
        float mean = red[0] / 36864.0f;
        float msw  = fmaxf(mean, 1e-8f);   // = 1/s_w
        sw_sh      = 1.0f / msw;           // = s_w
        msw_out[0] = msw;
    }
    __syncthreads();
    float s_w = sw_sh;
    #pragma unroll
    for (int i = 0; i < 144; ++i) {
        int idx = i * 256 + tid;                 // ((o*64+c)*3+kh)*3+kw
        float t = rintf(s_w * W[idx]);
        t = fminf(1.0f, fmaxf(-1.0f, t));
        int o  = idx / 576;
        int r  = idx - o * 576;
        int c  = r / 9;
        int r2 = r - c * 9;
        int kh = r2 / 3;
        int kw = r2 - kh * 3;
        int k  = (kh * 3 + kw) * 64 + c;
        tw2[((k >> 3) * 64 + o) * 8 + (k & 7)] = (_Float16)t;
    }
}

// ---------------------------------------------------------------------------
// Kernel 2: per-pixel channel-norm + int8 fake-quant, output f16 NHWC.
// One thread per pixel; 64 channel values live in VGPRs.
// ---------------------------------------------------------------------------
__global__ __launch_bounds__(256, 2) void norm_kernel(const float* __restrict__ x,
                                                      _Float16* __restrict__ y) {
    int p  = blockIdx.x * 256 + threadIdx.x;     // 0 .. 524287
    int bb = p >> 16;
    int hw = p & 65535;
    const float* xp = x + (size_t)bb * 64 * 65536 + hw;

    float v[64];
    float s = 0.0f;
    #pragma unroll
    for (int c = 0; c < 64; ++c) { v[c] = xp[(size_t)c * 65536]; s += v[c]; }
    float mu = s * (1.0f / 64.0f);

    float var = 0.0f, dmax = 0.0f;
    #pragma unroll
    for (int c = 0; c < 64; ++c) {
        float d = v[c] - mu;
        var += d * d;
        dmax = fmaxf(dmax, fabsf(d));
    }
    var *= (1.0f / 64.0f);
    float r    = 1.0f / sqrtf(var + 1e-8f);
    float amax = fmaxf(dmax * r, 1e-8f);
    float s_a  = 127.0f / amax;
    float invs = amax / 127.0f;

    half8 hv[8];
    #pragma unroll
    for (int c = 0; c < 64; ++c) {
        float yn = (v[c] - mu) * r;
        float q  = rintf(s_a * yn);                  // RNE == jnp.round
        q = fminf(127.0f, fmaxf(-128.0f, q));
        hv[c >> 3][c & 7] = (_Float16)(q * invs);
    }
    half8* yp = (half8*)(y + (size_t)p * 64);
    #pragma unroll
    for (int j = 0; j < 8; ++j) yp[j] = hv[j];
}

// ---------------------------------------------------------------------------
// Kernel 3: 3x3 conv as implicit GEMM on mfma_f32_16x16x32_f16.
// Block = (b, h, 64-wide w tile). 4 waves; wave wv owns o in [wv*16, wv*16+16).
// A = weights (M=o), B = activations (N=pixels) -> D cols = w -> coalesced.
// LDS tile layout [kh][c/8][w(66)][8] so B-fragments are single b128 reads.
// ---------------------------------------------------------------------------
__global__ __launch_bounds__(256, 2) void conv_kernel(const _Float16* __restrict__ y,
                                                      const _Float16* __restrict__ tw2,
                                                      const float* __restrict__ msw_p,
                                                      const float* __restrict__ bias,
                                                      float* __restrict__ out) {
    __shared__ alignas(16) _Float16 lds[3 * 8 * 66 * 8];   // 25344 B

    int tid = threadIdx.x;
    int bid = blockIdx.x;
    int wt = bid & 3;
    int h  = (bid >> 2) & 255;
    int bb = bid >> 10;
    int w0 = wt * 64;

    // ---- stage y halo tile (rows h-1..h+1, w0-1..w0+64, all 64 c) ----
    for (int i = tid; i < 1584; i += 256) {          // 3*66*8 half8-chunks
        int cc = i & 7;
        int t8 = i >> 3;                             // kh*66 + wl
        int wl = t8 % 66;
        int kh = t8 / 66;
        int hp = h + kh - 1;
        int wp = w0 + wl - 1;
        half8 val;
        #pragma unroll
        for (int e = 0; e < 8; ++e) val[e] = (_Float16)0.0f;
        if ((unsigned)hp < 256u && (unsigned)wp < 256u)
            val = *(const half8*)(y + ((((size_t)bb * 256 + hp) * 256 + wp) * 64 + cc * 8));
        *(half8*)(lds + ((kh * 8 + cc) * 66 + wl) * 8) = val;
    }

    int l   = tid & 63;
    int wv  = tid >> 6;
    int l15 = l & 15;
    int q8  = l >> 4;

    // ---- preload weight A-fragments (18 K-steps), L2-hot ----
    half8 aw[18];
    #pragma unroll
    for (int ks = 0; ks < 18; ++ks)
        aw[ks] = *(const half8*)(tw2 + (((ks * 4 + q8) * 64) + wv * 16 + l15) * 8);

    __syncthreads();

    f32x4 acc[4];
    #pragma unroll
    for (int nt = 0; nt < 4; ++nt)
        #pragma unroll
        for (int r2 = 0; r2 < 4; ++r2) acc[nt][r2] = 0.0f;

    #pragma unroll
    for (int ks = 0; ks < 18; ++ks) {
        int tap = ks >> 1;
        int kh  = tap / 3;
        int kw  = tap - kh * 3;
        int ccb = (ks & 1) * 4 + q8;
        int base = ((kh * 8 + ccb) * 66 + kw + l15) * 8;
        #pragma unroll
        for (int nt = 0; nt < 4; ++nt) {
            half8 bf = *(const half8*)(lds + base + nt * 128);
            acc[nt] = __builtin_amdgcn_mfma_f32_16x16x32_f16(aw[ks], bf, acc[nt], 0, 0, 0);
        }
    }

    // ---- epilogue: D[row=o_local=q8*4+reg][col=w=nt*16+l15] ----
    float msw = *msw_p;                 // = 1/s_w
    size_t obase = ((size_t)bb * 64) * 65536 + (size_t)h * 256;
    #pragma unroll
    for (int reg = 0; reg < 4; ++reg) {
        int o = wv * 16 + q8 * 4 + reg;
        float bo = bias[o];
        #pragma unroll
        for (int nt = 0; nt < 4; ++nt) {
            int w = w0 + nt * 16 + l15;
            out[obase + (size_t)o * 65536 + w] = acc[nt][reg] * msw + bo;
        }
    }
}

extern "C" void kernel_launch(void* const* d_in, const int* in_sizes, int n_in,
                              void* d_out, int out_size, void* d_ws, size_t ws_size,
                              hipStream_t stream) {
    const float* x = (const float*)d_in[0];   // [8,64,256,256]
    const float* W = (const float*)d_in[1];   // [64,64,3,3]
    const float* b = (const float*)d_in[2];   // [64]
    float* out = (float*)d_out;

    char* ws = (char*)d_ws;
    _Float16* y   = (_Float16*)(ws + Y_OFF);
    _Float16* tw2 = (_Float16*)(ws + TW_OFF);
    float*    msw = (float*)(ws + MSW_OFF);

    wq_kernel<<<1, 256, 0, stream>>>(W, tw2, msw);
    norm_kernel<<<2048, 256, 0, stream>>>(x, y);
    conv_kernel<<<8192, 256, 0, stream>>>(y, tw2, msw, b, out);
}